// Round 1
// baseline (1187.749 us; speedup 1.0000x reference)
//
#include <hip/hip_runtime.h>
#include <math.h>

// DCNv2: B=16, Cin=Cout=128, H=W=64, K=3, stride=1, pad=1 -> Ho=Wo=64, n=9 taps.
// Round 0: correctness-first f32 implementation.
//   k_transpose: x NCHW -> NHWC (xt) for contiguous per-channel bilinear reads
//   k_prep:      wt[n][c][o] = weight[o][c][n];  offwt[c][kyx][ch] = off_w[ch][c][kyx]
//   k_offconv:   offset/mask conv (27 ch/pixel), mask pre-sigmoided
//   k_fused:     per output row: for each tap, bilinear-sample S[128c][64p] into LDS,
//                then 4px x 8out register-tiled dot with W chunks staged in LDS.

#define B_    16
#define C_    128
#define CO_   128
#define H_    64
#define W_    64
#define HW_   4096
#define NT_   9
#define NOFF_ 27

// ---------------- kernel 1: NCHW -> NHWC ----------------
__global__ __launch_bounds__(256) void k_transpose(const float* __restrict__ x,
                                                   float* __restrict__ xt) {
    __shared__ float tile[32][129];
    int blk = blockIdx.x;
    int b   = blk >> 7;            // 128 blocks per batch
    int hw0 = (blk & 127) << 5;    // 32 hw positions per block
    int t   = threadIdx.x;
    int hwl = t & 31;
    int cg  = t >> 5;              // 0..7
    const float* src = x + (size_t)b * C_ * HW_;
#pragma unroll
    for (int i = 0; i < 16; ++i) {
        int c = cg + (i << 3);
        tile[hwl][c] = src[(size_t)c * HW_ + hw0 + hwl];
    }
    __syncthreads();
    float* dst = xt + ((size_t)b * HW_ + hw0) * C_;
    int c2 = t & 127;
    int hq = t >> 7;               // 0..1
#pragma unroll
    for (int j = 0; j < 16; ++j) {
        int hw = hq + (j << 1);
        dst[(size_t)hw * C_ + c2] = tile[hw][c2];
    }
}

// ---------------- kernel 2: weight reshapes ----------------
__global__ __launch_bounds__(256) void k_prep(const float* __restrict__ weight,
                                              const float* __restrict__ off_w,
                                              float* __restrict__ wt,
                                              float* __restrict__ offwt) {
    int idx = blockIdx.x * 256 + threadIdx.x;
    if (idx < NT_ * C_ * CO_) {
        int n = idx / (C_ * CO_);
        int r = idx % (C_ * CO_);
        int c = r / CO_;
        int o = r % CO_;
        wt[idx] = weight[((size_t)o * C_ + c) * NT_ + n];
    } else {
        int k = idx - NT_ * C_ * CO_;
        if (k < C_ * NT_ * NOFF_) {
            int c   = k / (NT_ * NOFF_);
            int r2  = k % (NT_ * NOFF_);
            int kyx = r2 / NOFF_;
            int ch  = r2 % NOFF_;
            offwt[k] = off_w[((size_t)ch * C_ + c) * NT_ + kyx];
        }
    }
}

// ---------------- kernel 3: offset/mask conv ----------------
__global__ __launch_bounds__(256) void k_offconv(const float* __restrict__ x,
                                                 const float* __restrict__ offwt,
                                                 const float* __restrict__ off_b,
                                                 float* __restrict__ offout) {
    int blk = blockIdx.x;                 // 256 blocks: b = blk>>4, 4 rows each
    int t   = threadIdx.x;
    int b   = blk >> 4;
    int ho  = ((blk & 15) << 2) + (t >> 6);
    int wo  = t & 63;
    float acc[NOFF_];
#pragma unroll
    for (int ch = 0; ch < NOFF_; ++ch) acc[ch] = off_b[ch];
    const float* xb = x + (size_t)b * C_ * HW_;
#pragma unroll 1
    for (int c = 0; c < C_; ++c) {
        const float* xc = xb + (size_t)c * HW_;
        const float* wc = offwt + c * NT_ * NOFF_;
#pragma unroll
        for (int ky = 0; ky < 3; ++ky) {
            int yy = ho + ky - 1;
            bool rv = (unsigned)yy < (unsigned)H_;
#pragma unroll
            for (int kx = 0; kx < 3; ++kx) {
                int xx = wo + kx - 1;
                float xv = (rv && (unsigned)xx < (unsigned)W_) ? xc[yy * W_ + xx] : 0.f;
                const float* wr = wc + (ky * 3 + kx) * NOFF_;
#pragma unroll
                for (int ch = 0; ch < NOFF_; ++ch) acc[ch] += xv * wr[ch];
            }
        }
    }
    int hw = (ho << 6) + wo;
    float* dst = offout + (size_t)b * NOFF_ * HW_ + hw;
#pragma unroll
    for (int ch = 0; ch < NOFF_; ++ch) {
        float v = acc[ch];
        if (ch >= 18) v = 1.f / (1.f + __expf(-v));  // pre-sigmoid the mask
        dst[(size_t)ch * HW_] = v;
    }
}

// ---------------- kernel 4: fused bilinear sample + einsum ----------------
__global__ __launch_bounds__(256) void k_fused(const float* __restrict__ xt,
                                               const float* __restrict__ offout,
                                               const float* __restrict__ wt,
                                               const float* __restrict__ bias,
                                               float* __restrict__ out) {
    __shared__ __align__(16) float S[C_][64];     // 32 KB  [c][p]
    __shared__ __align__(16) float Wl[32][CO_];   // 16 KB  [c_sub][o]
    int blk = blockIdx.x;          // 1024 blocks: one (b, ho) row each
    int b   = blk >> 6;
    int ho  = blk & 63;
    int t   = threadIdx.x;
    int p   = t & 63;              // sampling: pixel (=wo)
    int cq  = t >> 6;              // sampling: c-quarter 0..3
    int pgrp = t & 15, ogrp = t >> 4;
    int p0 = pgrp << 2, o0 = ogrp << 3;   // compute: 4 pixels x 8 outputs

    float acc[4][8];
#pragma unroll
    for (int i = 0; i < 4; ++i)
#pragma unroll
        for (int j = 0; j < 8; ++j) acc[i][j] = 0.f;

    const float* offb = offout + (size_t)b * NOFF_ * HW_ + (ho << 6) + p;
    const float* xtb  = xt + (size_t)b * HW_ * C_;

#pragma unroll 1
    for (int n = 0; n < NT_; ++n) {
        __syncthreads();
        // ---- bilinear sample tap n into S[c][p] ----
        float dy = offb[(size_t)(2 * n) * HW_];
        float dx = offb[(size_t)(2 * n + 1) * HW_];
        float m  = offb[(size_t)(18 + n) * HW_];
        float ys = (float)(ho + n / 3 - 1) + dy;
        float xs = (float)(p + n % 3 - 1) + dx;
        float y0f = floorf(ys), x0f = floorf(xs);
        float fy = ys - y0f, fx = xs - x0f;
        int y0 = (int)y0f, x0 = (int)x0f;
        float w00 = (1.f - fy) * (1.f - fx) * m;
        float w01 = (1.f - fy) * fx * m;
        float w10 = fy * (1.f - fx) * m;
        float w11 = fy * fx * m;
        bool vy0 = (unsigned)y0 < (unsigned)H_;
        bool vy1 = (unsigned)(y0 + 1) < (unsigned)H_;
        bool vx0 = (unsigned)x0 < (unsigned)W_;
        bool vx1 = (unsigned)(x0 + 1) < (unsigned)W_;
        int c0  = cq << 5;
        int i00 = (y0 * 64 + x0) * C_ + c0;
        int i01 = i00 + C_;
        int i10 = i00 + W_ * C_;
        int i11 = i10 + C_;
        const float4 fz = make_float4(0.f, 0.f, 0.f, 0.f);
#pragma unroll
        for (int k = 0; k < 8; ++k) {
            int kc = k << 2;
            float4 v00 = (vy0 && vx0) ? *(const float4*)&xtb[i00 + kc] : fz;
            float4 v01 = (vy0 && vx1) ? *(const float4*)&xtb[i01 + kc] : fz;
            float4 v10 = (vy1 && vx0) ? *(const float4*)&xtb[i10 + kc] : fz;
            float4 v11 = (vy1 && vx1) ? *(const float4*)&xtb[i11 + kc] : fz;
            int c = c0 + kc;
            S[c + 0][p] = w00 * v00.x + w01 * v01.x + w10 * v10.x + w11 * v11.x;
            S[c + 1][p] = w00 * v00.y + w01 * v01.y + w10 * v10.y + w11 * v11.y;
            S[c + 2][p] = w00 * v00.z + w01 * v01.z + w10 * v10.z + w11 * v11.z;
            S[c + 3][p] = w00 * v00.w + w01 * v01.w + w10 * v10.w + w11 * v11.w;
        }
        // ---- 4 c-chunks of 32: stage W, accumulate ----
#pragma unroll 1
        for (int cc = 0; cc < 4; ++cc) {
            __syncthreads();
            const float4* wsrc = (const float4*)(wt + ((size_t)(n * C_ + cc * 32)) * CO_);
            float4* wdst = (float4*)&Wl[0][0];
#pragma unroll
            for (int q = 0; q < 4; ++q) wdst[t + (q << 8)] = wsrc[t + (q << 8)];
            __syncthreads();
#pragma unroll 8
            for (int cs = 0; cs < 32; ++cs) {
                int c = (cc << 5) + cs;
                float4 sv = *(const float4*)&S[c][p0];
                float4 wa = *(const float4*)&Wl[cs][o0];
                float4 wb = *(const float4*)&Wl[cs][o0 + 4];
                float svv[4] = {sv.x, sv.y, sv.z, sv.w};
                float wvv[8] = {wa.x, wa.y, wa.z, wa.w, wb.x, wb.y, wb.z, wb.w};
#pragma unroll
                for (int i = 0; i < 4; ++i)
#pragma unroll
                    for (int j = 0; j < 8; ++j) acc[i][j] += svv[i] * wvv[j];
            }
        }
    }
    // ---- epilogue ----
    float* ob = out + (size_t)b * CO_ * HW_ + (ho << 6) + p0;
#pragma unroll
    for (int j = 0; j < 8; ++j) {
        int o = o0 + j;
        float bo = bias[o];
        float4 v = make_float4(acc[0][j] + bo, acc[1][j] + bo,
                               acc[2][j] + bo, acc[3][j] + bo);
        *(float4*)&ob[(size_t)o * HW_] = v;
    }
}

extern "C" void kernel_launch(void* const* d_in, const int* in_sizes, int n_in,
                              void* d_out, int out_size, void* d_ws, size_t ws_size,
                              hipStream_t stream) {
    const float* x      = (const float*)d_in[0];
    const float* weight = (const float*)d_in[1];
    const float* bias   = (const float*)d_in[2];
    const float* off_w  = (const float*)d_in[3];
    const float* off_b  = (const float*)d_in[4];
    float* out = (float*)d_out;

    // ws layout (floats): xt | offout | wt | offwt  -> ~41.3 MB total
    float* ws     = (float*)d_ws;
    float* xt     = ws;                        // 8388608
    float* offout = xt + (size_t)B_ * HW_ * C_;        // +1769472
    float* wt     = offout + (size_t)B_ * NOFF_ * HW_; // +147456
    float* offwt  = wt + (size_t)NT_ * C_ * CO_;       // +31104

    hipLaunchKernelGGL(k_transpose, dim3(2048), dim3(256), 0, stream, x, xt);
    int prep_total = NT_ * C_ * CO_ + C_ * NT_ * NOFF_;
    hipLaunchKernelGGL(k_prep, dim3((prep_total + 255) / 256), dim3(256), 0, stream,
                       weight, off_w, wt, offwt);
    hipLaunchKernelGGL(k_offconv, dim3(256), dim3(256), 0, stream, x, offwt, off_b, offout);
    hipLaunchKernelGGL(k_fused, dim3(1024), dim3(256), 0, stream, xt, offout, wt, bias, out);
}